// Round 1
// baseline (259.809 us; speedup 1.0000x reference)
//
#include <hip/hip_runtime.h>
#include <hip/hip_bf16.h>
#include <math.h>

typedef __bf16 bf16;
typedef __attribute__((ext_vector_type(8))) __bf16 bf16x8;
typedef __attribute__((ext_vector_type(4))) __bf16 bf16x4;
typedef __attribute__((ext_vector_type(4))) float f32x4;

#define B_  2
#define T_  2048
#define C_  1024
#define H_  16
#define HD_ 64
#define WIN_ 256

// ---------------- conversions ----------------

__global__ __launch_bounds__(256) void cvt_f32_bf16_k(const float* __restrict__ in,
                                                      bf16* __restrict__ out) {
  int idx = blockIdx.x * 256 + threadIdx.x;           // 4 elems per thread
  const float4 v = ((const float4*)in)[idx];
  bf16x4 o;
  o[0] = (bf16)v.x; o[1] = (bf16)v.y; o[2] = (bf16)v.z; o[3] = (bf16)v.w;
  ((bf16x4*)out)[idx] = o;
}

// W [K][N] f32  ->  WT [N][K] bf16
__global__ __launch_bounds__(256) void transpose_cvt_k(const float* __restrict__ W,
                                                       bf16* __restrict__ WT,
                                                       int K, int N) {
  __shared__ float t[32][33];
  int n0 = blockIdx.x * 32, k0 = blockIdx.y * 32;
  int tx = threadIdx.x, ty = threadIdx.y;
  #pragma unroll
  for (int i = 0; i < 32; i += 8)
    t[ty + i][tx] = W[(size_t)(k0 + ty + i) * N + (n0 + tx)];
  __syncthreads();
  #pragma unroll
  for (int i = 0; i < 32; i += 8)
    WT[(size_t)(n0 + ty + i) * K + (k0 + tx)] = (bf16)t[tx][ty + i];
}

// ---------------- bf16 MFMA GEMM ----------------
// C[M][N] = A[M][K] * Bt[N][K]^T + bias[N]
// 128x128 tile, BK=32, 256 threads = 4 waves (2x2 of 64x64)

template <bool OUT_BF16>
__global__ __launch_bounds__(256) void gemm_bf16_k(const bf16* __restrict__ A,
                                                   const bf16* __restrict__ Bt,
                                                   const float* __restrict__ bias,
                                                   void* __restrict__ Cout,
                                                   int M, int N, int K) {
  const int bm = blockIdx.x * 128;
  const int bn = blockIdx.y * 128;
  const int tid  = threadIdx.x;
  const int wid  = tid >> 6;
  const int lane = tid & 63;
  const int wm = (wid >> 1) * 64;
  const int wn = (wid & 1) * 64;
  const int lr = lane & 15;          // fragment row (A) / row of Bt (=N col)
  const int lk = (lane >> 4) * 8;    // fragment k offset

  __shared__ bf16 As[128][40];       // +8 pad keeps ds_read_b128 ~2-way
  __shared__ bf16 Bs[128][40];

  f32x4 acc[4][4] = {};

  for (int k0 = 0; k0 < K; k0 += 32) {
    __syncthreads();
    #pragma unroll
    for (int i = 0; i < 2; ++i) {
      int c   = tid + i * 256;       // 0..511 : 128 rows x 4 chunks of 8 bf16
      int row = c >> 2;
      int col = (c & 3) * 8;
      *(bf16x8*)&As[row][col] = *(const bf16x8*)&A [(size_t)(bm + row) * K + k0 + col];
      *(bf16x8*)&Bs[row][col] = *(const bf16x8*)&Bt[(size_t)(bn + row) * K + k0 + col];
    }
    __syncthreads();

    bf16x8 af[4], bfr[4];
    #pragma unroll
    for (int m = 0; m < 4; ++m) af[m]  = *(const bf16x8*)&As[wm + m * 16 + lr][lk];
    #pragma unroll
    for (int n = 0; n < 4; ++n) bfr[n] = *(const bf16x8*)&Bs[wn + n * 16 + lr][lk];

    #pragma unroll
    for (int m = 0; m < 4; ++m)
      #pragma unroll
      for (int n = 0; n < 4; ++n)
        acc[m][n] = __builtin_amdgcn_mfma_f32_16x16x32_bf16(af[m], bfr[n], acc[m][n], 0, 0, 0);
  }

  // epilogue: D elem (reg r, lane l) -> row=(l>>4)*4+r, col=l&15
  const int orow = (lane >> 4) * 4;
  const int ocol = lane & 15;
  #pragma unroll
  for (int m = 0; m < 4; ++m)
    #pragma unroll
    for (int n = 0; n < 4; ++n) {
      int gn = bn + wn + n * 16 + ocol;
      float bv = bias[gn];
      #pragma unroll
      for (int r = 0; r < 4; ++r) {
        int gm = bm + wm + m * 16 + orow + r;
        float val = acc[m][n][r] + bv;
        if (OUT_BF16) ((bf16*)Cout)[(size_t)gm * N + gn] = (bf16)val;
        else          ((float*)Cout)[(size_t)gm * N + gn] = val;
      }
    }
}

// ---------------- windowed flash attention ----------------
// qkv bf16 [B,T,3C]; y bf16 [B,T,C]. One block per (64 q rows, h, b).
// wave w handles rows r0=w*16 .. +15; lane = head dim for q/y, key idx for k.

__device__ inline float lane_bcast(float v, int l) {
  return __builtin_bit_cast(float, __builtin_amdgcn_readlane(__builtin_bit_cast(int, v), l));
}
__device__ inline float wred_max(float v) {
  #pragma unroll
  for (int o = 32; o > 0; o >>= 1) v = fmaxf(v, __shfl_xor(v, o, 64));
  return v;
}
__device__ inline float wred_sum(float v) {
  #pragma unroll
  for (int o = 32; o > 0; o >>= 1) v += __shfl_xor(v, o, 64);
  return v;
}

__global__ __launch_bounds__(256) void attn_k(const bf16* __restrict__ qkv,
                                              bf16* __restrict__ y) {
  const int q0 = blockIdx.x * 64;
  const int h  = blockIdx.y;
  const int b  = blockIdx.z;
  const int tid  = threadIdx.x;
  const int wid  = tid >> 6;
  const int lane = tid & 63;
  const int r0   = wid * 16;

  __shared__ float ks[64][65];
  __shared__ float vs[64][65];

  // q rows -> registers, pre-scaled
  float qreg[16];
  const size_t qbase = ((size_t)(b * T_ + q0 + r0)) * (3 * C_) + h * HD_ + lane;
  #pragma unroll
  for (int r = 0; r < 16; ++r)
    qreg[r] = 0.125f * (float)qkv[qbase + (size_t)r * (3 * C_)];

  float m[16], ls[16], yv[16];
  #pragma unroll
  for (int r = 0; r < 16; ++r) { m[r] = -1e30f; ls[r] = 0.f; yv[r] = 0.f; }

  const int kt_lo = (blockIdx.x >= 4) ? (int)blockIdx.x - 4 : 0;
  const int kt_hi = blockIdx.x;

  for (int kt = kt_lo; kt <= kt_hi; ++kt) {
    __syncthreads();
    // stage K,V tile (64 keys x 64 dims), bf16 -> f32
    #pragma unroll
    for (int i = 0; i < 2; ++i) {
      int c  = tid + i * 256;
      int kr = c >> 3;
      int d0 = (c & 7) * 8;
      size_t gk = ((size_t)(b * T_) + kt * 64 + kr) * (3 * C_) + C_ + h * HD_ + d0;
      bf16x8 kv = *(const bf16x8*)&qkv[gk];
      bf16x8 vv = *(const bf16x8*)&qkv[gk + C_];
      #pragma unroll
      for (int j = 0; j < 8; ++j) { ks[kr][d0 + j] = (float)kv[j]; vs[kr][d0 + j] = (float)vv[j]; }
    }
    __syncthreads();

    #pragma unroll
    for (int r = 0; r < 16; ++r) {
      float acc = 0.f;
      #pragma unroll
      for (int d = 0; d < 64; ++d)
        acc = fmaf(lane_bcast(qreg[r], d), ks[lane][d], acc);

      const int ig = q0 + r0 + r;
      const int jg = kt * 64 + lane;
      const bool valid = (jg <= ig) && (ig - jg <= WIN_);
      float s = valid ? acc : -__builtin_inff();

      float tmax = wred_max(s);
      float mnew = fmaxf(m[r], tmax);
      float alpha = __expf(m[r] - mnew);        // first tile: exp(-1e30-finite)=0
      float p = __expf(s - mnew);               // masked: exp(-inf)=0
      float tsum = wred_sum(p);
      ls[r] = ls[r] * alpha + tsum;
      float yr = yv[r] * alpha;
      #pragma unroll
      for (int l = 0; l < 64; ++l)
        yr = fmaf(lane_bcast(p, l), vs[l][lane], yr);
      yv[r] = yr;
      m[r]  = mnew;
    }
  }

  #pragma unroll
  for (int r = 0; r < 16; ++r) {
    float invl = 1.f / ls[r];
    y[((size_t)(b * T_ + q0 + r0 + r)) * C_ + h * HD_ + lane] = (bf16)(yv[r] * invl);
  }
}

// ---------------- launch ----------------

extern "C" void kernel_launch(void* const* d_in, const int* in_sizes, int n_in,
                              void* d_out, int out_size, void* d_ws, size_t ws_size,
                              hipStream_t stream) {
  const float* x     = (const float*)d_in[0];
  const float* Wqkv  = (const float*)d_in[1];
  const float* bqkv  = (const float*)d_in[2];
  const float* Wproj = (const float*)d_in[3];
  const float* bproj = (const float*)d_in[4];
  // d_in[5] = mask : computed analytically, never read
  float* out = (float*)d_out;

  const size_t SZ_QKV = (size_t)B_ * T_ * 3 * C_ * sizeof(bf16); // 25165824
  const size_t SZ_XB  = (size_t)B_ * T_ * C_ * sizeof(bf16);     //  8388608
  const size_t SZ_WQT = (size_t)3 * C_ * C_ * sizeof(bf16);      //  6291456
  const size_t SZ_WPT = (size_t)C_ * C_ * sizeof(bf16);          //  2097152
  const size_t NEED   = SZ_QKV + SZ_XB + SZ_WQT + SZ_WPT + SZ_XB;
  if (ws_size < NEED) return;

  char* ws = (char*)d_ws;
  bf16* qkvb   = (bf16*)(ws);
  bf16* xb     = (bf16*)(ws + SZ_QKV);
  bf16* wqkvT  = (bf16*)(ws + SZ_QKV + SZ_XB);
  bf16* wprojT = (bf16*)(ws + SZ_QKV + SZ_XB + SZ_WQT);
  bf16* yb     = (bf16*)(ws + SZ_QKV + SZ_XB + SZ_WQT + SZ_WPT);

  // x -> bf16 : 4,194,304 elems / 4 per thread / 256 per block
  cvt_f32_bf16_k<<<4096, 256, 0, stream>>>(x, xb);
  // Wqkv [1024][3072] -> [3072][1024] bf16
  transpose_cvt_k<<<dim3(3 * C_ / 32, C_ / 32), dim3(32, 8), 0, stream>>>(Wqkv, wqkvT, C_, 3 * C_);
  // Wproj [1024][1024] -> [1024][1024] bf16 (transposed)
  transpose_cvt_k<<<dim3(C_ / 32, C_ / 32), dim3(32, 8), 0, stream>>>(Wproj, wprojT, C_, C_);

  // qkv = x @ Wqkv + bqkv  (bf16 out)
  gemm_bf16_k<true><<<dim3((B_ * T_) / 128, (3 * C_) / 128), 256, 0, stream>>>(
      xb, wqkvT, bqkv, qkvb, B_ * T_, 3 * C_, C_);

  // windowed attention
  attn_k<<<dim3(T_ / 64, H_, B_), 256, 0, stream>>>(qkvb, yb);

  // out = y @ Wproj + bproj  (f32 out)
  gemm_bf16_k<false><<<dim3((B_ * T_) / 128, C_ / 128), 256, 0, stream>>>(
      yb, wprojT, bproj, out, B_ * T_, C_, C_);
}

// Round 2
// 102.274 us; speedup vs baseline: 2.5403x; 2.5403x over previous
//
#include <hip/hip_runtime.h>
#include <hip/hip_bf16.h>
#include <math.h>

typedef __bf16 bf16;
typedef __attribute__((ext_vector_type(8))) __bf16 bf16x8;
typedef __attribute__((ext_vector_type(4))) __bf16 bf16x4;
typedef __attribute__((ext_vector_type(4))) float f32x4;

#define B_  2
#define T_  2048
#define C_  1024
#define H_  16
#define HD_ 64
#define WIN_ 256

// ---------------- conversions ----------------

__global__ __launch_bounds__(256) void cvt_f32_bf16_k(const float* __restrict__ in,
                                                      bf16* __restrict__ out) {
  int idx = blockIdx.x * 256 + threadIdx.x;           // 4 elems per thread
  const float4 v = ((const float4*)in)[idx];
  bf16x4 o;
  o[0] = (bf16)v.x; o[1] = (bf16)v.y; o[2] = (bf16)v.z; o[3] = (bf16)v.w;
  ((bf16x4*)out)[idx] = o;
}

// W [K][N] f32  ->  WT [N][K] bf16
__global__ __launch_bounds__(256) void transpose_cvt_k(const float* __restrict__ W,
                                                       bf16* __restrict__ WT,
                                                       int K, int N) {
  __shared__ float t[32][33];
  int n0 = blockIdx.x * 32, k0 = blockIdx.y * 32;
  int tx = threadIdx.x, ty = threadIdx.y;
  #pragma unroll
  for (int i = 0; i < 32; i += 8)
    t[ty + i][tx] = W[(size_t)(k0 + ty + i) * N + (n0 + tx)];
  __syncthreads();
  #pragma unroll
  for (int i = 0; i < 32; i += 8)
    WT[(size_t)(n0 + ty + i) * K + (k0 + tx)] = (bf16)t[tx][ty + i];
}

// ---------------- bf16 MFMA GEMM ----------------
// C[M][N] = A[M][K] * Bt[N][K]^T + bias[N]
// 128x128 tile, BK=32, 256 threads = 4 waves (2x2 of 64x64)
// MODE 0: f32 out, stride N.
// MODE 2: qkv split: cols [0,2C) -> bf16 out0 stride 2C;
//                    cols [2C,3C) -> V^T layout out1[(b*H+h)*64+d][tok] bf16.

template <int MODE>
__global__ __launch_bounds__(256) void gemm_bf16_k(const bf16* __restrict__ A,
                                                   const bf16* __restrict__ Bt,
                                                   const float* __restrict__ bias,
                                                   void* __restrict__ out0,
                                                   void* __restrict__ out1,
                                                   int M, int N, int K) {
  const int bm = blockIdx.x * 128;
  const int bn = blockIdx.y * 128;
  const int tid  = threadIdx.x;
  const int wid  = tid >> 6;
  const int lane = tid & 63;
  const int wm = (wid >> 1) * 64;
  const int wn = (wid & 1) * 64;
  const int lr = lane & 15;          // fragment row
  const int lk = (lane >> 4) * 8;    // fragment k offset

  __shared__ bf16 As[128][40];
  __shared__ bf16 Bs[128][40];

  f32x4 acc[4][4] = {};

  for (int k0 = 0; k0 < K; k0 += 32) {
    __syncthreads();
    #pragma unroll
    for (int i = 0; i < 2; ++i) {
      int c   = tid + i * 256;       // 512 chunks: 128 rows x 4 chunks of 8 bf16
      int row = c >> 2;
      int col = (c & 3) * 8;
      *(bf16x8*)&As[row][col] = *(const bf16x8*)&A [(size_t)(bm + row) * K + k0 + col];
      *(bf16x8*)&Bs[row][col] = *(const bf16x8*)&Bt[(size_t)(bn + row) * K + k0 + col];
    }
    __syncthreads();

    bf16x8 af[4], bfr[4];
    #pragma unroll
    for (int m = 0; m < 4; ++m) af[m]  = *(const bf16x8*)&As[wm + m * 16 + lr][lk];
    #pragma unroll
    for (int n = 0; n < 4; ++n) bfr[n] = *(const bf16x8*)&Bs[wn + n * 16 + lr][lk];

    #pragma unroll
    for (int m = 0; m < 4; ++m)
      #pragma unroll
      for (int n = 0; n < 4; ++n)
        acc[m][n] = __builtin_amdgcn_mfma_f32_16x16x32_bf16(af[m], bfr[n], acc[m][n], 0, 0, 0);
  }

  // epilogue: D elem (reg r, lane l) -> row=(l>>4)*4+r, col=l&15
  const int orow = (lane >> 4) * 4;
  const int ocol = lane & 15;
  #pragma unroll
  for (int m = 0; m < 4; ++m)
    #pragma unroll
    for (int n = 0; n < 4; ++n) {
      const int gn = bn + wn + n * 16 + ocol;
      const int gm0 = bm + wm + m * 16 + orow;
      const float bv = bias[gn];
      if (MODE == 0) {
        #pragma unroll
        for (int r = 0; r < 4; ++r)
          ((float*)out0)[(size_t)(gm0 + r) * N + gn] = acc[m][n][r] + bv;
      } else { // MODE 2
        if (bn < 2 * C_) {
          #pragma unroll
          for (int r = 0; r < 4; ++r)
            ((bf16*)out0)[(size_t)(gm0 + r) * (2 * C_) + gn] = (bf16)(acc[m][n][r] + bv);
        } else {
          const int vcol = gn - 2 * C_;
          const int h = vcol >> 6, d = vcol & 63;
          const int b = gm0 >> 11, tok = gm0 & (T_ - 1);   // gm0 % 4 == 0
          bf16x4 o;
          #pragma unroll
          for (int r = 0; r < 4; ++r) o[r] = (bf16)(acc[m][n][r] + bv);
          *(bf16x4*)&((bf16*)out1)[(((size_t)b * H_ + h) * HD_ + d) * T_ + tok] = o;
        }
      }
    }
}

// ---------------- windowed flash attention (MFMA) ----------------
// qk  bf16 [B,T,2C] (Q | K); vt bf16 [B,H,64,T] (V^T); y bf16 [B,T,C].
// Block: 4 waves, 64 q rows for one (b,h). Wave w owns rows w*16..+15.
// Swapped QK^T: sacc[t] = mfma(Kfrag, Qfrag) -> S^T[key=t*16+g*4+r][q=lr].

__global__ __launch_bounds__(256) void attn_mfma_k(const bf16* __restrict__ qk,
                                                   const bf16* __restrict__ vt,
                                                   bf16* __restrict__ y) {
  const int q0 = blockIdx.x * 64;
  const int h  = blockIdx.y;
  const int b  = blockIdx.z;
  const int tid  = threadIdx.x;
  const int wid  = tid >> 6;
  const int lane = tid & 63;
  const int lr = lane & 15;
  const int g  = lane >> 4;

  __shared__ bf16 Ks[64][72];          // [key][d]
  __shared__ bf16 Vs[64][72];          // [d][key]  (V^T)
  __shared__ bf16 Ps[4][16][72];       // per-wave: [q][key]

  // Q fragments (B-operand): row=lr -> q row, k = s*32 + g*8 + i
  const int qrow = q0 + wid * 16 + lr;
  const bf16* qptr = qk + ((size_t)(b * T_ + qrow)) * (2 * C_) + h * HD_;
  bf16x8 qf[2];
  qf[0] = *(const bf16x8*)(qptr + g * 8);
  qf[1] = *(const bf16x8*)(qptr + 32 + g * 8);

  float m = -1e30f, l = 0.f;           // online stats for q row = lr
  f32x4 yacc[4] = {};                  // Y[q=g*4+r][d=t*16+lr]

  const int kt_lo = (blockIdx.x >= 4) ? (int)blockIdx.x - 4 : 0;
  for (int kt = kt_lo; kt <= (int)blockIdx.x; ++kt) {
    __syncthreads();
    #pragma unroll
    for (int i = 0; i < 2; ++i) {
      int cc = tid + i * 256;          // 512 chunks
      int rr = cc >> 3;                // key row (K) / d row (Vt)
      int c0 = (cc & 7) * 8;
      *(bf16x8*)&Ks[rr][c0] = *(const bf16x8*)&qk[((size_t)(b * T_) + kt * 64 + rr) * (2 * C_) + C_ + h * HD_ + c0];
      *(bf16x8*)&Vs[rr][c0] = *(const bf16x8*)&vt[(((size_t)b * H_ + h) * HD_ + rr) * T_ + kt * 64 + c0];
    }
    __syncthreads();

    // S^T = K @ Q^T
    f32x4 sacc[4] = {};
    #pragma unroll
    for (int t = 0; t < 4; ++t)
      #pragma unroll
      for (int s = 0; s < 2; ++s)
        sacc[t] = __builtin_amdgcn_mfma_f32_16x16x32_bf16(
            *(const bf16x8*)&Ks[t * 16 + lr][s * 32 + g * 8], qf[s], sacc[t], 0, 0, 0);

    // mask + scale, row max over this tile
    float pv[4][4];
    float rmax = -1e30f;
    #pragma unroll
    for (int t = 0; t < 4; ++t)
      #pragma unroll
      for (int r = 0; r < 4; ++r) {
        const int key = kt * 64 + t * 16 + g * 4 + r;
        const bool valid = (key <= qrow) && (qrow - key <= WIN_);
        const float sv = valid ? sacc[t][r] * 0.125f : -__builtin_inff();
        pv[t][r] = sv;
        rmax = fmaxf(rmax, sv);
      }
    rmax = fmaxf(rmax, __shfl_xor(rmax, 16));
    rmax = fmaxf(rmax, __shfl_xor(rmax, 32));

    const float mnew = fmaxf(m, rmax);
    const float alpha = __expf(m - mnew);
    m = mnew;
    float lsum = 0.f;
    #pragma unroll
    for (int t = 0; t < 4; ++t)
      #pragma unroll
      for (int r = 0; r < 4; ++r) {
        const float e = __expf(pv[t][r] - mnew);
        pv[t][r] = e;
        lsum += e;
      }
    lsum += __shfl_xor(lsum, 16);
    lsum += __shfl_xor(lsum, 32);
    l = l * alpha + lsum;

    // P -> LDS (bf16), layout [q=lr][key]
    #pragma unroll
    for (int t = 0; t < 4; ++t) {
      bf16x4 pk;
      #pragma unroll
      for (int r = 0; r < 4; ++r) pk[r] = (bf16)pv[t][r];
      *(bf16x4*)&Ps[wid][lr][t * 16 + g * 4] = pk;
    }

    // rescale Y acc (rows q = g*4+r)
    float al[4];
    #pragma unroll
    for (int r = 0; r < 4; ++r) al[r] = __shfl(alpha, g * 4 + r);
    #pragma unroll
    for (int t = 0; t < 4; ++t)
      #pragma unroll
      for (int r = 0; r < 4; ++r) yacc[t][r] *= al[r];

    // PV: Y += P @ V   (A = P [q][key], B = V^T [d][key])
    bf16x8 pf[2];
    pf[0] = *(const bf16x8*)&Ps[wid][lr][g * 8];
    pf[1] = *(const bf16x8*)&Ps[wid][lr][32 + g * 8];
    #pragma unroll
    for (int t = 0; t < 4; ++t)
      #pragma unroll
      for (int s = 0; s < 2; ++s)
        yacc[t] = __builtin_amdgcn_mfma_f32_16x16x32_bf16(
            pf[s], *(const bf16x8*)&Vs[t * 16 + lr][s * 32 + g * 8], yacc[t], 0, 0, 0);
  }

  // epilogue
  float li[4];
  #pragma unroll
  for (int r = 0; r < 4; ++r) li[r] = 1.f / __shfl(l, g * 4 + r);
  #pragma unroll
  for (int t = 0; t < 4; ++t)
    #pragma unroll
    for (int r = 0; r < 4; ++r) {
      const int tok = q0 + wid * 16 + g * 4 + r;
      y[((size_t)(b * T_ + tok)) * C_ + h * HD_ + t * 16 + lr] = (bf16)(yacc[t][r] * li[r]);
    }
}

// ---------------- launch ----------------

extern "C" void kernel_launch(void* const* d_in, const int* in_sizes, int n_in,
                              void* d_out, int out_size, void* d_ws, size_t ws_size,
                              hipStream_t stream) {
  const float* x     = (const float*)d_in[0];
  const float* Wqkv  = (const float*)d_in[1];
  const float* bqkv  = (const float*)d_in[2];
  const float* Wproj = (const float*)d_in[3];
  const float* bproj = (const float*)d_in[4];
  float* out = (float*)d_out;

  const size_t SZ_QK  = (size_t)B_ * T_ * 2 * C_ * sizeof(bf16); // 16 MB
  const size_t SZ_VT  = (size_t)B_ * H_ * HD_ * T_ * sizeof(bf16); // 8 MB
  const size_t SZ_XB  = (size_t)B_ * T_ * C_ * sizeof(bf16);     // 8 MB
  const size_t SZ_WQT = (size_t)3 * C_ * C_ * sizeof(bf16);      // 6 MB
  const size_t SZ_WPT = (size_t)C_ * C_ * sizeof(bf16);          // 2 MB
  const size_t NEED   = SZ_QK + SZ_VT + SZ_XB + SZ_WQT + SZ_WPT + SZ_XB;
  if (ws_size < NEED) return;

  char* ws = (char*)d_ws;
  bf16* qkb    = (bf16*)(ws);
  bf16* vtb    = (bf16*)(ws + SZ_QK);
  bf16* xb     = (bf16*)(ws + SZ_QK + SZ_VT);
  bf16* wqkvT  = (bf16*)(ws + SZ_QK + SZ_VT + SZ_XB);
  bf16* wprojT = (bf16*)(ws + SZ_QK + SZ_VT + SZ_XB + SZ_WQT);
  bf16* yb     = (bf16*)(ws + SZ_QK + SZ_VT + SZ_XB + SZ_WQT + SZ_WPT);

  cvt_f32_bf16_k<<<4096, 256, 0, stream>>>(x, xb);
  transpose_cvt_k<<<dim3(3 * C_ / 32, C_ / 32), dim3(32, 8), 0, stream>>>(Wqkv, wqkvT, C_, 3 * C_);
  transpose_cvt_k<<<dim3(C_ / 32, C_ / 32), dim3(32, 8), 0, stream>>>(Wproj, wprojT, C_, C_);

  // qkv = x @ Wqkv + bqkv  (Q,K -> qkb [B,T,2C]; V -> vtb [B,H,64,T])
  gemm_bf16_k<2><<<dim3((B_ * T_) / 128, (3 * C_) / 128), 256, 0, stream>>>(
      xb, wqkvT, bqkv, qkb, vtb, B_ * T_, 3 * C_, C_);

  attn_mfma_k<<<dim3(T_ / 64, H_, B_), 256, 0, stream>>>(qkb, vtb, yb);

  // out = y @ Wproj + bproj (f32)
  gemm_bf16_k<0><<<dim3((B_ * T_) / 128, C_ / 128), 256, 0, stream>>>(
      yb, wprojT, bproj, out, nullptr, B_ * T_, C_, C_);
}

// Round 3
// 96.949 us; speedup vs baseline: 2.6799x; 1.0549x over previous
//
#include <hip/hip_runtime.h>
#include <hip/hip_bf16.h>
#include <math.h>

typedef __bf16 bf16;
typedef __attribute__((ext_vector_type(8))) __bf16 bf16x8;
typedef __attribute__((ext_vector_type(4))) __bf16 bf16x4;
typedef __attribute__((ext_vector_type(4))) float f32x4;

#define B_  2
#define T_  2048
#define C_  1024
#define H_  16
#define HD_ 64
#define WIN_ 256

// async global->LDS, 16B per lane, dest = wave-uniform base + lane*16
#define GLOAD16(g, l)                                                        \
  __builtin_amdgcn_global_load_lds(                                          \
      (const __attribute__((address_space(1))) void*)(g),                    \
      (__attribute__((address_space(3))) void*)(l), 16, 0, 0)

// ---------------- conversions ----------------

__global__ __launch_bounds__(256) void cvt_f32_bf16_k(const float* __restrict__ in,
                                                      bf16* __restrict__ out) {
  int idx = blockIdx.x * 256 + threadIdx.x;           // 4 elems per thread
  const float4 v = ((const float4*)in)[idx];
  bf16x4 o;
  o[0] = (bf16)v.x; o[1] = (bf16)v.y; o[2] = (bf16)v.z; o[3] = (bf16)v.w;
  ((bf16x4*)out)[idx] = o;
}

// W [K][N] f32  ->  WT [N][K] bf16
__global__ __launch_bounds__(256) void transpose_cvt_k(const float* __restrict__ W,
                                                       bf16* __restrict__ WT,
                                                       int K, int N) {
  __shared__ float t[32][33];
  int n0 = blockIdx.x * 32, k0 = blockIdx.y * 32;
  int tx = threadIdx.x, ty = threadIdx.y;
  #pragma unroll
  for (int i = 0; i < 32; i += 8)
    t[ty + i][tx] = W[(size_t)(k0 + ty + i) * N + (n0 + tx)];
  __syncthreads();
  #pragma unroll
  for (int i = 0; i < 32; i += 8)
    WT[(size_t)(n0 + ty + i) * K + (k0 + tx)] = (bf16)t[tx][ty + i];
}

// ---------------- bf16 MFMA GEMM (m97 structure) ----------------
// C[M][N] = A[M][K] * Bt[N][K]^T + bias[N]
// BM x 128 tile, BK=32, 256 threads = 4 waves (2x2), global_load_lds staging.
// MODE 0: f32 out stride N.
// MODE 2: qkv split: cols [0,2C) -> bf16 out0 stride 2C;
//                    cols [2C,3C) -> V^T layout out1[((b*H+h)*64+d)*T+tok].

template <int BM, int MODE>
__global__ __launch_bounds__(256) void gemm_lds_k(const bf16* __restrict__ A,
                                                  const bf16* __restrict__ Bt,
                                                  const float* __restrict__ bias,
                                                  void* __restrict__ out0,
                                                  void* __restrict__ out1,
                                                  int M, int N, int K) {
  constexpr int FM = BM / 32;          // A-fragments per wave
  const int bm = blockIdx.x * BM;
  const int bn = blockIdx.y * 128;
  const int tid  = threadIdx.x;
  const int wid  = tid >> 6;
  const int lane = tid & 63;
  const int wm = (wid >> 1) * (BM / 2);
  const int wn = (wid & 1) * 64;
  const int lr = lane & 15;
  const int g  = lane >> 4;

  __shared__ bf16 As[BM][32];          // linear, 64 B rows (gload_lds needs no pad)
  __shared__ bf16 Bs[128][32];

  f32x4 acc[FM][4] = {};

  // staging: 1 KB chunk = 16 rows x 64 B; lane -> (row = lane>>2, 16B piece = lane&3)
  const int srow = lane >> 2;
  const int scol = (lane & 3) * 8;
  const bf16* Abase = A  + (size_t)bm * K;
  const bf16* Bbase = Bt + (size_t)bn * K;

  for (int k0 = 0; k0 < K; k0 += 32) {
    #pragma unroll
    for (int i = 0; i < BM / 64; ++i) {
      const int c = wid * (BM / 64) + i;
      GLOAD16(Abase + (size_t)(c * 16 + srow) * K + k0 + scol, &As[c * 16][0]);
    }
    #pragma unroll
    for (int i = 0; i < 2; ++i) {
      const int c = wid * 2 + i;
      GLOAD16(Bbase + (size_t)(c * 16 + srow) * K + k0 + scol, &Bs[c * 16][0]);
    }
    __syncthreads();                    // vmcnt(0) drain + barrier: LDS ready

    bf16x8 af[FM], bfr[4];
    #pragma unroll
    for (int m = 0; m < FM; ++m) af[m]  = *(const bf16x8*)&As[wm + m * 16 + lr][g * 8];
    #pragma unroll
    for (int n = 0; n < 4; ++n)  bfr[n] = *(const bf16x8*)&Bs[wn + n * 16 + lr][g * 8];

    #pragma unroll
    for (int m = 0; m < FM; ++m)
      #pragma unroll
      for (int n = 0; n < 4; ++n)
        acc[m][n] = __builtin_amdgcn_mfma_f32_16x16x32_bf16(af[m], bfr[n], acc[m][n], 0, 0, 0);
    __syncthreads();                    // all reads done before next stage
  }

  // epilogue: D elem (reg r, lane l) -> row=(l>>4)*4+r, col=l&15
  const int orow = g * 4;
  const int ocol = lr;
  #pragma unroll
  for (int m = 0; m < FM; ++m)
    #pragma unroll
    for (int n = 0; n < 4; ++n) {
      const int gn  = bn + wn + n * 16 + ocol;
      const int gm0 = bm + wm + m * 16 + orow;
      const float bv = bias[gn];
      if (MODE == 0) {
        #pragma unroll
        for (int r = 0; r < 4; ++r)
          ((float*)out0)[(size_t)(gm0 + r) * N + gn] = acc[m][n][r] + bv;
      } else { // MODE 2
        if (bn < 2 * C_) {
          #pragma unroll
          for (int r = 0; r < 4; ++r)
            ((bf16*)out0)[(size_t)(gm0 + r) * (2 * C_) + gn] = (bf16)(acc[m][n][r] + bv);
        } else {
          const int vcol = gn - 2 * C_;
          const int h = vcol >> 6, d = vcol & 63;
          const int b = gm0 >> 11, tok = gm0 & (T_ - 1);   // gm0 % 4 == 0
          bf16x4 o;
          #pragma unroll
          for (int r = 0; r < 4; ++r) o[r] = (bf16)(acc[m][n][r] + bv);
          *(bf16x4*)&((bf16*)out1)[(((size_t)b * H_ + h) * HD_ + d) * T_ + tok] = o;
        }
      }
    }
}

// ---------------- windowed flash attention (MFMA) ----------------
// qk  bf16 [B,T,2C] (Q | K); vt bf16 [B,H,64,T] (V^T); y bf16 [B,T,C].
// Block: 4 waves, 64 q rows for one (b,h). Wave w owns rows w*16..+15.
// Swapped QK^T: sacc[t] = mfma(Kfrag, Qfrag) -> S^T[key=t*16+g*4+r][q=lr].

__global__ __launch_bounds__(256) void attn_mfma_k(const bf16* __restrict__ qk,
                                                   const bf16* __restrict__ vt,
                                                   bf16* __restrict__ y) {
  const int q0 = blockIdx.x * 64;
  const int h  = blockIdx.y;
  const int b  = blockIdx.z;
  const int tid  = threadIdx.x;
  const int wid  = tid >> 6;
  const int lane = tid & 63;
  const int lr = lane & 15;
  const int g  = lane >> 4;

  __shared__ bf16 Ks[64][72];          // [key][d]
  __shared__ bf16 Vs[64][72];          // [d][key]  (V^T)
  __shared__ bf16 Ps[4][16][72];       // per-wave: [q][key]

  // Q fragments (B-operand): row=lr -> q row, k = s*32 + g*8 + i
  const int qrow = q0 + wid * 16 + lr;
  const bf16* qptr = qk + ((size_t)(b * T_ + qrow)) * (2 * C_) + h * HD_;
  bf16x8 qf[2];
  qf[0] = *(const bf16x8*)(qptr + g * 8);
  qf[1] = *(const bf16x8*)(qptr + 32 + g * 8);

  float m = -1e30f, l = 0.f;           // online stats for q row = lr
  f32x4 yacc[4] = {};                  // Y[q=g*4+r][d=t*16+lr]

  const int kt_lo = (blockIdx.x >= 4) ? (int)blockIdx.x - 4 : 0;
  for (int kt = kt_lo; kt <= (int)blockIdx.x; ++kt) {
    __syncthreads();
    #pragma unroll
    for (int i = 0; i < 2; ++i) {
      int cc = tid + i * 256;          // 512 chunks
      int rr = cc >> 3;                // key row (K) / d row (Vt)
      int c0 = (cc & 7) * 8;
      *(bf16x8*)&Ks[rr][c0] = *(const bf16x8*)&qk[((size_t)(b * T_) + kt * 64 + rr) * (2 * C_) + C_ + h * HD_ + c0];
      *(bf16x8*)&Vs[rr][c0] = *(const bf16x8*)&vt[(((size_t)b * H_ + h) * HD_ + rr) * T_ + kt * 64 + c0];
    }
    __syncthreads();

    // S^T = K @ Q^T
    f32x4 sacc[4] = {};
    #pragma unroll
    for (int t = 0; t < 4; ++t)
      #pragma unroll
      for (int s = 0; s < 2; ++s)
        sacc[t] = __builtin_amdgcn_mfma_f32_16x16x32_bf16(
            *(const bf16x8*)&Ks[t * 16 + lr][s * 32 + g * 8], qf[s], sacc[t], 0, 0, 0);

    // mask + scale, row max over this tile
    float pv[4][4];
    float rmax = -1e30f;
    #pragma unroll
    for (int t = 0; t < 4; ++t)
      #pragma unroll
      for (int r = 0; r < 4; ++r) {
        const int key = kt * 64 + t * 16 + g * 4 + r;
        const bool valid = (key <= qrow) && (qrow - key <= WIN_);
        const float sv = valid ? sacc[t][r] * 0.125f : -__builtin_inff();
        pv[t][r] = sv;
        rmax = fmaxf(rmax, sv);
      }
    rmax = fmaxf(rmax, __shfl_xor(rmax, 16));
    rmax = fmaxf(rmax, __shfl_xor(rmax, 32));

    const float mnew = fmaxf(m, rmax);
    const float alpha = __expf(m - mnew);
    m = mnew;
    float lsum = 0.f;
    #pragma unroll
    for (int t = 0; t < 4; ++t)
      #pragma unroll
      for (int r = 0; r < 4; ++r) {
        const float e = __expf(pv[t][r] - mnew);
        pv[t][r] = e;
        lsum += e;
      }
    lsum += __shfl_xor(lsum, 16);
    lsum += __shfl_xor(lsum, 32);
    l = l * alpha + lsum;

    // P -> LDS (bf16), layout [q=lr][key]
    #pragma unroll
    for (int t = 0; t < 4; ++t) {
      bf16x4 pk;
      #pragma unroll
      for (int r = 0; r < 4; ++r) pk[r] = (bf16)pv[t][r];
      *(bf16x4*)&Ps[wid][lr][t * 16 + g * 4] = pk;
    }

    // rescale Y acc (rows q = g*4+r)
    float al[4];
    #pragma unroll
    for (int r = 0; r < 4; ++r) al[r] = __shfl(alpha, g * 4 + r);
    #pragma unroll
    for (int t = 0; t < 4; ++t)
      #pragma unroll
      for (int r = 0; r < 4; ++r) yacc[t][r] *= al[r];

    // PV: Y += P @ V   (A = P [q][key], B = V^T [d][key])
    bf16x8 pf[2];
    pf[0] = *(const bf16x8*)&Ps[wid][lr][g * 8];
    pf[1] = *(const bf16x8*)&Ps[wid][lr][32 + g * 8];
    #pragma unroll
    for (int t = 0; t < 4; ++t)
      #pragma unroll
      for (int s = 0; s < 2; ++s)
        yacc[t] = __builtin_amdgcn_mfma_f32_16x16x32_bf16(
            pf[s], *(const bf16x8*)&Vs[t * 16 + lr][s * 32 + g * 8], yacc[t], 0, 0, 0);
  }

  // epilogue
  float li[4];
  #pragma unroll
  for (int r = 0; r < 4; ++r) li[r] = 1.f / __shfl(l, g * 4 + r);
  #pragma unroll
  for (int t = 0; t < 4; ++t)
    #pragma unroll
    for (int r = 0; r < 4; ++r) {
      const int tok = q0 + wid * 16 + g * 4 + r;
      y[((size_t)(b * T_ + tok)) * C_ + h * HD_ + t * 16 + lr] = (bf16)(yacc[t][r] * li[r]);
    }
}

// ---------------- launch ----------------

extern "C" void kernel_launch(void* const* d_in, const int* in_sizes, int n_in,
                              void* d_out, int out_size, void* d_ws, size_t ws_size,
                              hipStream_t stream) {
  const float* x     = (const float*)d_in[0];
  const float* Wqkv  = (const float*)d_in[1];
  const float* bqkv  = (const float*)d_in[2];
  const float* Wproj = (const float*)d_in[3];
  const float* bproj = (const float*)d_in[4];
  float* out = (float*)d_out;

  const size_t SZ_QK  = (size_t)B_ * T_ * 2 * C_ * sizeof(bf16);   // 16 MB
  const size_t SZ_VT  = (size_t)B_ * H_ * HD_ * T_ * sizeof(bf16); //  8 MB
  const size_t SZ_XB  = (size_t)B_ * T_ * C_ * sizeof(bf16);       //  8 MB
  const size_t SZ_WQT = (size_t)3 * C_ * C_ * sizeof(bf16);        //  6 MB
  const size_t SZ_WPT = (size_t)C_ * C_ * sizeof(bf16);            //  2 MB
  const size_t NEED   = SZ_QK + SZ_VT + SZ_XB + SZ_WQT + SZ_WPT + SZ_XB;
  if (ws_size < NEED) return;

  char* ws = (char*)d_ws;
  bf16* qkb    = (bf16*)(ws);
  bf16* vtb    = (bf16*)(ws + SZ_QK);
  bf16* xb     = (bf16*)(ws + SZ_QK + SZ_VT);
  bf16* wqkvT  = (bf16*)(ws + SZ_QK + SZ_VT + SZ_XB);
  bf16* wprojT = (bf16*)(ws + SZ_QK + SZ_VT + SZ_XB + SZ_WQT);
  bf16* yb     = (bf16*)(ws + SZ_QK + SZ_VT + SZ_XB + SZ_WQT + SZ_WPT);

  cvt_f32_bf16_k<<<4096, 256, 0, stream>>>(x, xb);
  transpose_cvt_k<<<dim3(3 * C_ / 32, C_ / 32), dim3(32, 8), 0, stream>>>(Wqkv, wqkvT, C_, 3 * C_);
  transpose_cvt_k<<<dim3(C_ / 32, C_ / 32), dim3(32, 8), 0, stream>>>(Wproj, wprojT, C_, C_);

  // qkv = x @ Wqkv + bqkv  (Q,K -> qkb [B,T,2C]; V -> vtb [B,H,64,T])
  gemm_lds_k<128, 2><<<dim3((B_ * T_) / 128, (3 * C_) / 128), 256, 0, stream>>>(
      xb, wqkvT, bqkv, qkb, vtb, B_ * T_, 3 * C_, C_);

  attn_mfma_k<<<dim3(T_ / 64, H_, B_), 256, 0, stream>>>(qkb, vtb, yb);

  // out = y @ Wproj + bproj (f32), BM=64 -> 512 blocks for occupancy
  gemm_lds_k<64, 0><<<dim3((B_ * T_) / 64, C_ / 128), 256, 0, stream>>>(
      yb, wprojT, bproj, out, nullptr, B_ * T_, C_, C_);
}